// Round 4
// baseline (634.718 us; speedup 1.0000x reference)
//
#include <hip/hip_runtime.h>

#define BB 4
#define CC 64
#define TT 32
#define HWN 1024          // H*W
#define PP 32768          // H*W*T

// All fp32: inputs fp32 (proven by detector invariance r2 vs r3), output fp32
// buffer (harness instructions; compare-side casts to bf16). Scratch need is
// only 395 KB: q/k/v are recomputed from x in consumers (no 48 MB staging).

// ---------------- K1: style vectors  s[b][0..63]=qkv, s[b][64..127]=proj ---
__global__ __launch_bounds__(128) void k_style(
        const float* __restrict__ style, const float* __restrict__ qkv_lw,
        const float* __restrict__ qkv_lb, const float* __restrict__ proj_lw,
        const float* __restrict__ proj_lb, float* __restrict__ s_out) {
    int b = blockIdx.x, tid = threadIdx.x;
    const float *lw, *lb; int i;
    if (tid < 64) { lw = qkv_lw; lb = qkv_lb; i = tid; }
    else          { lw = proj_lw; lb = proj_lb; i = tid - 64; }
    const float* st = style + b * 512;
    const float* w  = lw + (size_t)i * 512;
    float a0 = 0.f, a1 = 0.f, a2 = 0.f, a3 = 0.f;
    for (int k = 0; k < 512; k += 4) {
        float4 sv = *(const float4*)(st + k);
        float4 wv = *(const float4*)(w + k);
        a0 = fmaf(sv.x, wv.x, a0); a1 = fmaf(sv.y, wv.y, a1);
        a2 = fmaf(sv.z, wv.z, a2); a3 = fmaf(sv.w, wv.w, a3);
    }
    s_out[b * 128 + tid] = (a0 + a1) + (a2 + a3) + lb[i];
}

// ---------------- K2: normalized modulated weights -------------------------
__global__ __launch_bounds__(64) void k_wnorm(
        const float* __restrict__ qkv_w, const float* __restrict__ proj_w,
        const float* __restrict__ s, float* __restrict__ wq, float* __restrict__ wp) {
    int id = blockIdx.x;           // 4 * 256
    int b = id >> 8, o = id & 255, i = threadIdx.x;
    float wv; float* dst;
    if (o < 192) { wv = qkv_w[o * 64 + i] * s[b * 128 + i];               dst = wq + (b * 192 + o) * 64; }
    else { int oo = o - 192; wv = proj_w[oo * 64 + i] * s[b * 128 + 64 + i]; dst = wp + (b * 64 + oo) * 64; }
    float sq = wv * wv;
    #pragma unroll
    for (int off = 32; off > 0; off >>= 1) sq += __shfl_xor(sq, off, 64);
    dst[i] = wv * rsqrtf(sq + 1e-8f);
}

// ---------------- K3: scores, q/k recomputed from x ------------------------
// block = (b, hwblk of 16 hw); all 8 heads per block; atomic partial into S.
__global__ __launch_bounds__(256) void k_scores(
        const float* __restrict__ x, const float* __restrict__ wq,
        const float* __restrict__ qnp, const float* __restrict__ qbp,
        const float* __restrict__ qnoise, float* __restrict__ S) {
    int bidx = blockIdx.x;            // 4 * 64
    int b = bidx >> 6, hwblk = bidx & 63;
    int tid = threadIdx.x, wave = tid >> 6, lane = tid & 63;
    int ig = lane >> 3, jg = lane & 7;
    __shared__ float xs[64][512];     // 128 KB: x[ch][16hw*32t]
    __shared__ float qs[8][256];
    __shared__ float ks[8][256];
    const float* xb = x + (size_t)b * CC * PP + hwblk * 512;
    #pragma unroll 4
    for (int r = 0; r < 128; ++r) {
        int idx = r * 256 + tid;
        xs[idx >> 9][idx & 511] = xb[(size_t)(idx >> 9) * PP + (idx & 511)];
    }
    float nvh0 = qnoise[(size_t)b * PP + hwblk * 512 + tid];
    float nvh1 = qnoise[(size_t)b * PP + hwblk * 512 + 256 + tid];
    float* Sb0 = S + (size_t)b * 8192;
    for (int n = 0; n < 8; ++n) {
        float acc[16];
        #pragma unroll
        for (int q = 0; q < 16; ++q) acc[q] = 0.f;
        const float* wqq = wq + (b * 192 + n * 8) * 64;   // q rows (uniform -> s_load)
        const float* wqk = wqq + 64 * 64;                 // k rows
        for (int half = 0; half < 2; ++half) {
            __syncthreads();          // stage done / prior readers done
            float qa[8], ka[8];
            #pragma unroll
            for (int c = 0; c < 8; ++c) { qa[c] = 0.f; ka[c] = 0.f; }
            int p = half * 256 + tid;
            for (int i = 0; i < 64; ++i) {
                float xv = xs[i][p];
                #pragma unroll
                for (int c = 0; c < 8; ++c) {
                    qa[c] = fmaf(wqq[c * 64 + i], xv, qa[c]);
                    ka[c] = fmaf(wqk[c * 64 + i], xv, ka[c]);
                }
            }
            float nv = half ? nvh1 : nvh0;
            #pragma unroll
            for (int c = 0; c < 8; ++c) {
                qs[c][tid] = qa[c] + qnp[n * 8 + c] * nv + qbp[n * 8 + c];
                ks[c][tid] = ka[c] + qnp[64 + n * 8 + c] * nv + qbp[64 + n * 8 + c];
            }
            __syncthreads();
            #pragma unroll
            for (int e0 = 0; e0 < 16; ++e0) {             // e = c*8 + hw_local
                int e = wave * 16 + e0, c = e >> 3, hl = e & 7;
                float4 qv = *(const float4*)&qs[c][hl * 32 + ig * 4];
                float4 kv = *(const float4*)&ks[c][hl * 32 + jg * 4];
                float qa4[4] = {qv.x, qv.y, qv.z, qv.w};
                float ka4[4] = {kv.x, kv.y, kv.z, kv.w};
                #pragma unroll
                for (int ii = 0; ii < 4; ++ii)
                    #pragma unroll
                    for (int jj = 0; jj < 4; ++jj)
                        acc[ii * 4 + jj] = fmaf(qa4[ii], ka4[jj], acc[ii * 4 + jj]);
            }
        }
        float* Sb = Sb0 + n * 1024;
        #pragma unroll
        for (int ii = 0; ii < 4; ++ii)
            #pragma unroll
            for (int jj = 0; jj < 4; ++jj)
                atomicAdd(&Sb[(ig * 4 + ii) * 32 + jg * 4 + jj], acc[ii * 4 + jj]);
    }
}

// ---------------- K4: ALiBi + mask + softmax (in place) --------------------
__global__ __launch_bounds__(1024) void k_softmax(float* __restrict__ S) {
    int bn = blockIdx.x;                // b*8 + n
    int n = bn & 7;
    int tid = threadIdx.x, i = tid >> 5, j = tid & 31;
    float* row = S + (size_t)bn * 1024 + i * 32;
    float v = row[j] * 0.011048543456039806f;      // 1/sqrt(8192)
    float slope = exp2f(-(float)(n + 1));
    v -= slope * fabsf((float)(i - j));
    if (j <= i) v = -1e18f;                        // tril (incl. diag) masked
    float m = v;
    #pragma unroll
    for (int off = 16; off > 0; off >>= 1) m = fmaxf(m, __shfl_xor(m, off, 32));
    float e = expf(v - m);
    float s2 = e;
    #pragma unroll
    for (int off = 16; off > 0; off >>= 1) s2 += __shfl_xor(s2, off, 32);
    row[j] = e / s2;
}

// ---------------- K5: v recompute + PV + proj + noise/bias -----------------
__global__ __launch_bounds__(256) void k_out(
        const float* __restrict__ x, const float* __restrict__ wq,
        const float* __restrict__ qnp, const float* __restrict__ qbp,
        const float* __restrict__ qnoise, const float* __restrict__ P,
        const float* __restrict__ wp, const float* __restrict__ pnp,
        const float* __restrict__ pbp, const float* __restrict__ pnoise,
        float* __restrict__ out) {
    int bidx = blockIdx.x;              // 4 * 256
    int b = bidx >> 8, hw0 = (bidx & 255) * 4;
    int tid = threadIdx.x;
    __shared__ float Ps[8192];          // P[h][t][j]
    __shared__ float xs[64][128];       // x[ch][4hw*32t]
    __shared__ float As[64 * 132];      // A[i][t*4 + hwl], pad 132
    const float* Pb = P + (size_t)b * 8192;
    const float* xb = x + (size_t)b * CC * PP + (size_t)hw0 * 32;
    #pragma unroll
    for (int r = 0; r < 32; ++r) Ps[r * 256 + tid] = Pb[r * 256 + tid];
    #pragma unroll
    for (int r = 0; r < 32; ++r) {
        int idx = r * 256 + tid;
        xs[idx >> 7][idx & 127] = xb[(size_t)(idx >> 7) * PP + (idx & 127)];
    }
    __syncthreads();
    {   // v recompute + A[i,hwl,t] = sum_j P[i>>3,t,j] * v[i,hwl,j]
        int ich = tid >> 2, hwl = tid & 3, h = ich >> 3;
        const float* wv = wq + (size_t)(b * 192 + 128 + ich) * 64;
        float vreg[32];
        #pragma unroll
        for (int t = 0; t < 32; ++t) vreg[t] = 0.f;
        for (int i = 0; i < 64; ++i) {
            float wvi = wv[i];
            const float* xr = &xs[i][hwl * 32];
            #pragma unroll
            for (int t = 0; t < 32; ++t) vreg[t] = fmaf(wvi, xr[t], vreg[t]);
        }
        float npv = qnp[128 + ich], bpv = qbp[128 + ich];
        const float* nzr = qnoise + (size_t)b * PP + (size_t)(hw0 + hwl) * 32;
        #pragma unroll
        for (int t = 0; t < 32; ++t) vreg[t] = vreg[t] + bpv + npv * nzr[t];
        const float* Ph = Ps + h * 1024;
        #pragma unroll 4
        for (int t = 0; t < 32; ++t) {
            const float* Prow = Ph + t * 32;
            float a0 = 0.f, a1 = 0.f, a2 = 0.f, a3 = 0.f;
            #pragma unroll
            for (int j = 0; j < 32; j += 4) {
                float4 p4 = *(const float4*)(Prow + j);
                a0 = fmaf(p4.x, vreg[j],     a0);
                a1 = fmaf(p4.y, vreg[j + 1], a1);
                a2 = fmaf(p4.z, vreg[j + 2], a2);
                a3 = fmaf(p4.w, vreg[j + 3], a3);
            }
            As[ich * 132 + t * 4 + hwl] = (a0 + a1) + (a2 + a3);
        }
    }
    __syncthreads();
    {   // proj: out[o,hwl,t] = sum_i wp[o,i] * A[i,hwl,t] + pnp*noise + pbp
        int og = tid >> 6, lane = tid & 63;
        int t = lane & 31, rep = lane >> 5;
        int ogu = __builtin_amdgcn_readfirstlane(og);
        const float* wpb = wp + (b * 64 + ogu * 16) * 64;   // uniform -> s_load
        float acc[16][2];
        #pragma unroll
        for (int oo = 0; oo < 16; ++oo) { acc[oo][0] = 0.f; acc[oo][1] = 0.f; }
        #pragma unroll 4
        for (int i = 0; i < 64; ++i) {
            float2 a2v = *(const float2*)&As[i * 132 + t * 4 + rep * 2];
            #pragma unroll
            for (int oo = 0; oo < 16; ++oo) {
                float wvv = wpb[oo * 64 + i];
                acc[oo][0] = fmaf(wvv, a2v.x, acc[oo][0]);
                acc[oo][1] = fmaf(wvv, a2v.y, acc[oo][1]);
            }
        }
        float nz0 = pnoise[(size_t)b * PP + (size_t)(hw0 + rep * 2) * 32 + t];
        float nz1 = pnoise[(size_t)b * PP + (size_t)(hw0 + rep * 2 + 1) * 32 + t];
        #pragma unroll
        for (int oo = 0; oo < 16; ++oo) {
            int o = ogu * 16 + oo;
            float npv = pnp[o], bpv = pbp[o];
            size_t base = (size_t)(b * 64 + o) * PP + t;
            out[base + (size_t)(hw0 + rep * 2) * 32]     = acc[oo][0] + npv * nz0 + bpv;
            out[base + (size_t)(hw0 + rep * 2 + 1) * 32] = acc[oo][1] + npv * nz1 + bpv;
        }
    }
}

// ---------------- sentinels ------------------------------------------------
__global__ __launch_bounds__(256) void k_zero(float* __restrict__ out, int n) {
    int i = blockIdx.x * 256 + threadIdx.x;
    if (i < n) out[i] = 0.f;
}
__global__ void k_code(float* __restrict__ out, float code) { out[0] = code; }

extern "C" void kernel_launch(void* const* d_in, const int* in_sizes, int n_in,
                              void* d_out, int out_size, void* d_ws, size_t ws_size,
                              hipStream_t stream) {
    float* out = (float*)d_out;
    const int exp_sizes[14] = {4*64*32768, 4*512, 192*64, 64*512, 64, 192, 192,
                               4*32768, 64*64, 64*512, 64, 64, 64, 4*32768};
    bool ok = (n_in == 14) && (out_size == 4*64*32768);
    if (ok) for (int k = 0; k < 14; ++k) ok = ok && (in_sizes[k] == exp_sizes[k]);
    if (!ok) {  // shape-model tripwire: absmax ~= 1000
        k_zero<<<(out_size + 255) / 256, 256, 0, stream>>>(out, out_size);
        k_code<<<1, 1, 0, stream>>>(out, 1000.f);
        return;
    }
    if (ws_size < 395264) {  // ws tripwire: absmax ~= 2000 + MB
        k_zero<<<(out_size + 255) / 256, 256, 0, stream>>>(out, out_size);
        k_code<<<1, 1, 0, stream>>>(out, 2000.f + (float)(ws_size >> 20));
        return;
    }
    char* ws = (char*)d_ws;
    float* s_sty = (float*)ws;               //   2 KB
    float* wq    = (float*)(ws + 2048);      // 192 KB  (4,192,64)
    float* wp    = (float*)(ws + 198656);    //  64 KB  (4,64,64)
    float* S     = (float*)(ws + 264192);    // 128 KB  (4,8,32,32)

    hipMemsetAsync(S, 0, 131072, stream);
    k_style  <<<4,    128,  0, stream>>>((const float*)d_in[1], (const float*)d_in[3],
                                         (const float*)d_in[4], (const float*)d_in[9],
                                         (const float*)d_in[10], s_sty);
    k_wnorm  <<<1024, 64,   0, stream>>>((const float*)d_in[2], (const float*)d_in[8],
                                         s_sty, wq, wp);
    k_scores <<<256,  256,  0, stream>>>((const float*)d_in[0], wq,
                                         (const float*)d_in[5], (const float*)d_in[6],
                                         (const float*)d_in[7], S);
    k_softmax<<<32,   1024, 0, stream>>>(S);
    k_out    <<<1024, 256,  0, stream>>>((const float*)d_in[0], wq,
                                         (const float*)d_in[5], (const float*)d_in[6],
                                         (const float*)d_in[7], S, wp,
                                         (const float*)d_in[11], (const float*)d_in[12],
                                         (const float*)d_in[13], out);
    hipError_t e = hipGetLastError();
    if (e != hipSuccess) {  // launch-config tripwire: absmax ~= 3000 + code
        k_zero<<<(out_size + 255) / 256, 256, 0, stream>>>(out, out_size);
        k_code<<<1, 1, 0, stream>>>(out, 3000.f + (float)e);
    }
}

// Round 5
// 235.103 us; speedup vs baseline: 2.6997x; 2.6997x over previous
//
#include <hip/hip_runtime.h>

typedef unsigned short u16;
typedef unsigned int   u32;

#define PP 32768          // H*W*T
#define CC 64

// Pipeline: k_style -> k_wnorm (writes transposed weights) -> k_qk (q,k bf16
// into d_out-as-scratch) -> k_scores (S partials, LDS-reduced atomics) ->
// k_softmax -> k_out (v recompute + PV + proj, overwrites d_out with final).
// d_out as scratch is safe: same-stream ordering; k_out writes last.

__device__ __forceinline__ u16 f2b(float f) {
    u32 u; __builtin_memcpy(&u, &f, 4);
    u32 r = (u + 0x7FFFu + ((u >> 16) & 1u)) >> 16;
    return (u16)r;
}
__device__ __forceinline__ void unpack2(u32 v, float& lo, float& hi) {
    u32 a = v << 16; u32 b = v & 0xFFFF0000u;
    __builtin_memcpy(&lo, &a, 4); __builtin_memcpy(&hi, &b, 4);
}

// ---------------- K1: style vectors  s[b][0..63]=qkv, s[b][64..127]=proj ---
__global__ __launch_bounds__(128) void k_style(
        const float* __restrict__ style, const float* __restrict__ qkv_lw,
        const float* __restrict__ qkv_lb, const float* __restrict__ proj_lw,
        const float* __restrict__ proj_lb, float* __restrict__ s_out) {
    int b = blockIdx.x, tid = threadIdx.x;
    const float *lw, *lb; int i;
    if (tid < 64) { lw = qkv_lw; lb = qkv_lb; i = tid; }
    else          { lw = proj_lw; lb = proj_lb; i = tid - 64; }
    const float* st = style + b * 512;
    const float* w  = lw + (size_t)i * 512;
    float a0 = 0.f, a1 = 0.f, a2 = 0.f, a3 = 0.f;
    for (int k = 0; k < 512; k += 4) {
        float4 sv = *(const float4*)(st + k);
        float4 wv = *(const float4*)(w + k);
        a0 = fmaf(sv.x, wv.x, a0); a1 = fmaf(sv.y, wv.y, a1);
        a2 = fmaf(sv.z, wv.z, a2); a3 = fmaf(sv.w, wv.w, a3);
    }
    s_out[b * 128 + tid] = (a0 + a1) + (a2 + a3) + lb[i];
}

// ---------------- K2: normalized modulated weights, TRANSPOSED layouts -----
// wqkT[b][e][o] o<128 (q,k rows);  wvT[b][e][c] (v rows);  wpT[b][i][o] (proj)
__global__ __launch_bounds__(64) void k_wnorm(
        const float* __restrict__ qkv_w, const float* __restrict__ proj_w,
        const float* __restrict__ s, float* __restrict__ wqkT,
        float* __restrict__ wvT, float* __restrict__ wpT) {
    int id = blockIdx.x;           // 4 * 256
    int b = id >> 8, o = id & 255, i = threadIdx.x;
    float wv;
    if (o < 192) wv = qkv_w[o * 64 + i] * s[b * 128 + i];
    else         wv = proj_w[(o - 192) * 64 + i] * s[b * 128 + 64 + i];
    float sq = wv * wv;
    #pragma unroll
    for (int off = 32; off > 0; off >>= 1) sq += __shfl_xor(sq, off, 64);
    float val = wv * rsqrtf(sq + 1e-8f);
    if (o < 128)      wqkT[((size_t)b * 64 + i) * 128 + o]      = val;
    else if (o < 192) wvT [((size_t)b * 64 + i) * 64 + (o-128)] = val;
    else              wpT [((size_t)b * 64 + i) * 64 + (o-192)] = val;
}

// ---------------- K3: q,k materialization (bf16 into scratch) --------------
// grid (b, ptile64) = 2048; wave w -> out-rows [32w,32w+32); 16 KB LDS.
__global__ __launch_bounds__(256) void k_qk(
        const float* __restrict__ x, const float* __restrict__ wqkT,
        const float* __restrict__ qnp, const float* __restrict__ qbp,
        const float* __restrict__ qnoise, u16* __restrict__ qk) {
    int bidx = blockIdx.x;
    int b = bidx >> 9, p0 = (bidx & 511) * 64;
    int tid = threadIdx.x, pl = tid & 63;
    int wu = __builtin_amdgcn_readfirstlane(tid >> 6);
    __shared__ float xs[64][64];
    const float* xb = x + (size_t)b * CC * PP + p0;
    #pragma unroll
    for (int r = 0; r < 16; ++r) {
        int idx = r * 256 + tid;
        xs[idx >> 6][idx & 63] = xb[(size_t)(idx >> 6) * PP + (idx & 63)];
    }
    __syncthreads();
    const float* wt = wqkT + (size_t)b * 8192 + wu * 32;  // +e*128: contiguous 32
    float acc[32];
    #pragma unroll
    for (int o = 0; o < 32; ++o) acc[o] = 0.f;
    #pragma unroll 2
    for (int e = 0; e < 64; ++e) {
        float xv = xs[e][pl];
        const float* we = wt + e * 128;   // wave-uniform -> s_load
        #pragma unroll
        for (int o = 0; o < 32; ++o) acc[o] = fmaf(we[o], xv, acc[o]);
    }
    float nv = qnoise[(size_t)b * PP + p0 + pl];
    u16* ob = qk + ((size_t)b * 128 + wu * 32) * PP + p0 + pl;
    #pragma unroll
    for (int oo = 0; oo < 32; ++oo) {
        int o = wu * 32 + oo;
        float y = acc[oo] + qnp[o] * nv + qbp[o];
        ob[(size_t)oo * PP] = f2b(y);
    }
}

// ---------------- K4: attention scores (bf16 q,k -> fp32 S partials) -------
// grid (b, n, chunk32hw) = 1024; 64 KB LDS -> 2 blocks/CU.
__global__ __launch_bounds__(256) void k_scores(
        const u16* __restrict__ qk, float* __restrict__ S) {
    int bidx = blockIdx.x;
    int b = bidx >> 8, n = (bidx >> 5) & 7, chunk = bidx & 31;
    int tid = threadIdx.x, wave = tid >> 6, lane = tid & 63;
    int ig = lane >> 3, jg = lane & 7;
    __shared__ float q_lds[8192];     // [c][hw_l*32+t]
    __shared__ float k_lds[8192];
    const u16* qg = qk + ((size_t)b * 128 + n * 8) * PP + chunk * 1024;
    const u16* kg = qg + (size_t)64 * PP;
    #pragma unroll
    for (int r = 0; r < 4; ++r) {
        int idx = r * 256 + tid;      // 0..1023
        int c = idx >> 7, off = (idx & 127) * 8;
        uint4 qp = *(const uint4*)(qg + (size_t)c * PP + off);
        uint4 kp = *(const uint4*)(kg + (size_t)c * PP + off);
        float f[8];
        unpack2(qp.x, f[0], f[1]); unpack2(qp.y, f[2], f[3]);
        unpack2(qp.z, f[4], f[5]); unpack2(qp.w, f[6], f[7]);
        *(float4*)&q_lds[c * 1024 + off]     = make_float4(f[0], f[1], f[2], f[3]);
        *(float4*)&q_lds[c * 1024 + off + 4] = make_float4(f[4], f[5], f[6], f[7]);
        unpack2(kp.x, f[0], f[1]); unpack2(kp.y, f[2], f[3]);
        unpack2(kp.z, f[4], f[5]); unpack2(kp.w, f[6], f[7]);
        *(float4*)&k_lds[c * 1024 + off]     = make_float4(f[0], f[1], f[2], f[3]);
        *(float4*)&k_lds[c * 1024 + off + 4] = make_float4(f[4], f[5], f[6], f[7]);
    }
    __syncthreads();
    float acc[16];
    #pragma unroll
    for (int q = 0; q < 16; ++q) acc[q] = 0.f;
    #pragma unroll 4
    for (int i = 0; i < 64; ++i) {
        int e = wave * 64 + i, c = e >> 5, hl = e & 31;
        float4 qv = *(const float4*)&q_lds[c * 1024 + hl * 32 + ig * 4];
        float4 kv = *(const float4*)&k_lds[c * 1024 + hl * 32 + jg * 4];
        float qa4[4] = {qv.x, qv.y, qv.z, qv.w};
        float ka4[4] = {kv.x, kv.y, kv.z, kv.w};
        #pragma unroll
        for (int ii = 0; ii < 4; ++ii)
            #pragma unroll
            for (int jj = 0; jj < 4; ++jj)
                acc[ii * 4 + jj] = fmaf(qa4[ii], ka4[jj], acc[ii * 4 + jj]);
    }
    __syncthreads();                  // q_lds dead -> reduction scratch
    #pragma unroll
    for (int t = 0; t < 16; ++t) q_lds[t * 256 + tid] = acc[t];
    __syncthreads();
    if (wave == 0) {
        float* Sb = S + ((size_t)b * 8 + n) * 1024;
        #pragma unroll
        for (int t = 0; t < 16; ++t) {
            float s2 = q_lds[t * 256 + lane]       + q_lds[t * 256 + 64 + lane]
                     + q_lds[t * 256 + 128 + lane] + q_lds[t * 256 + 192 + lane];
            int ii = t >> 2, jj = t & 3;
            atomicAdd(&Sb[(ig * 4 + ii) * 32 + jg * 4 + jj], s2);
        }
    }
}

// ---------------- K5: ALiBi + mask + softmax (in place) --------------------
__global__ __launch_bounds__(1024) void k_softmax(float* __restrict__ S) {
    int bn = blockIdx.x;                // b*8 + n
    int n = bn & 7;
    int tid = threadIdx.x, i = tid >> 5, j = tid & 31;
    float* row = S + (size_t)bn * 1024 + i * 32;
    float v = row[j] * 0.011048543456039806f;      // 1/sqrt(8192)
    float slope = exp2f(-(float)(n + 1));
    v -= slope * fabsf((float)(i - j));
    if (j <= i) v = -1e18f;                        // tril (incl. diag) masked
    float m = v;
    #pragma unroll
    for (int off = 16; off > 0; off >>= 1) m = fmaxf(m, __shfl_xor(m, off, 32));
    float e = expf(v - m);
    float s2 = e;
    #pragma unroll
    for (int off = 16; off > 0; off >>= 1) s2 += __shfl_xor(s2, off, 32);
    row[j] = e / s2;
}

// ---------------- K6: v recompute + PV + proj (union LDS: 66.5 KB) ---------
__global__ __launch_bounds__(256) void k_out(
        const float* __restrict__ x, const float* __restrict__ wvT,
        const float* __restrict__ qnp, const float* __restrict__ qbp,
        const float* __restrict__ qnoise, const float* __restrict__ P,
        const float* __restrict__ wpT, const float* __restrict__ pnp,
        const float* __restrict__ pbp, const float* __restrict__ pnoise,
        float* __restrict__ out) {
    int bidx = blockIdx.x;              // 4 * 256
    int b = bidx >> 8, hw0 = (bidx & 255) * 4;
    int tid = threadIdx.x;
    __shared__ float Ps[8192];          // P[h][t][j]
    __shared__ float uni[64 * 132];     // phase 1: xs[64][128]; phase 2: As[64][132]
    const float* Pb = P + (size_t)b * 8192;
    const float* xb = x + (size_t)b * CC * PP + (size_t)hw0 * 32;
    #pragma unroll
    for (int r = 0; r < 32; ++r) Ps[r * 256 + tid] = Pb[r * 256 + tid];
    #pragma unroll
    for (int r = 0; r < 32; ++r) {
        int idx = r * 256 + tid;
        uni[(idx >> 7) * 128 + (idx & 127)] = xb[(size_t)(idx >> 7) * PP + (idx & 127)];
    }
    __syncthreads();
    int ich = tid >> 2, hwl = tid & 3, h = ich >> 3;
    float vreg[32];
    #pragma unroll
    for (int t = 0; t < 32; ++t) vreg[t] = 0.f;
    const float* wvb = wvT + (size_t)b * 4096 + ich;  // +e*64: 16 words/wave, 1 seg
    for (int e = 0; e < 64; ++e) {
        float wvi = wvb[(size_t)e * 64];
        const float* xr = &uni[e * 128 + hwl * 32];
        #pragma unroll
        for (int t = 0; t < 32; ++t) vreg[t] = fmaf(wvi, xr[t], vreg[t]);
    }
    float npv = qnp[128 + ich], bpv = qbp[128 + ich];
    const float* nzr = qnoise + (size_t)b * PP + (size_t)(hw0 + hwl) * 32;
    #pragma unroll
    for (int t = 0; t < 32; ++t) vreg[t] = vreg[t] + bpv + npv * nzr[t];
    __syncthreads();                    // all xs reads done -> uni becomes As
    const float* Ph = Ps + h * 1024;
    #pragma unroll 4
    for (int t = 0; t < 32; ++t) {      // A[ich, hwl, t] = sum_j P[h,t,j] v[j]
        const float* Prow = Ph + t * 32;
        float a0 = 0.f, a1 = 0.f, a2 = 0.f, a3 = 0.f;
        #pragma unroll
        for (int j = 0; j < 32; j += 4) {
            float4 p4 = *(const float4*)(Prow + j);
            a0 = fmaf(p4.x, vreg[j],     a0);
            a1 = fmaf(p4.y, vreg[j + 1], a1);
            a2 = fmaf(p4.z, vreg[j + 2], a2);
            a3 = fmaf(p4.w, vreg[j + 3], a3);
        }
        uni[ich * 132 + t * 4 + hwl] = (a0 + a1) + (a2 + a3);
    }
    __syncthreads();
    {   // proj: out[o,hwl,t] = sum_i wpT[b][i][o] * A[i,hwl,t] + noise/bias
        int og = tid >> 6, lane = tid & 63;
        int tt = lane & 31, rep = lane >> 5;
        int ogu = __builtin_amdgcn_readfirstlane(og);
        const float* wpt = wpT + (size_t)b * 4096 + ogu * 16;  // +i*64: contig 16
        float acc[16][2];
        #pragma unroll
        for (int oo = 0; oo < 16; ++oo) { acc[oo][0] = 0.f; acc[oo][1] = 0.f; }
        #pragma unroll 4
        for (int i = 0; i < 64; ++i) {
            float2 a2v = *(const float2*)&uni[i * 132 + tt * 4 + rep * 2];
            const float* wr = wpt + i * 64;   // wave-uniform -> s_load_dwordx16
            #pragma unroll
            for (int oo = 0; oo < 16; ++oo) {
                acc[oo][0] = fmaf(wr[oo], a2v.x, acc[oo][0]);
                acc[oo][1] = fmaf(wr[oo], a2v.y, acc[oo][1]);
            }
        }
        float nz0 = pnoise[(size_t)b * PP + (size_t)(hw0 + rep * 2) * 32 + tt];
        float nz1 = pnoise[(size_t)b * PP + (size_t)(hw0 + rep * 2 + 1) * 32 + tt];
        #pragma unroll
        for (int oo = 0; oo < 16; ++oo) {
            int o = ogu * 16 + oo;
            float npv2 = pnp[o], bpv2 = pbp[o];
            size_t base = (size_t)(b * 64 + o) * PP + tt;
            out[base + (size_t)(hw0 + rep * 2) * 32]     = acc[oo][0] + npv2 * nz0 + bpv2;
            out[base + (size_t)(hw0 + rep * 2 + 1) * 32] = acc[oo][1] + npv2 * nz1 + bpv2;
        }
    }
}

// ---------------- sentinels ------------------------------------------------
__global__ __launch_bounds__(256) void k_zero(float* __restrict__ out, int n) {
    int i = blockIdx.x * 256 + threadIdx.x;
    if (i < n) out[i] = 0.f;
}
__global__ void k_code(float* __restrict__ out, float code) { out[0] = code; }

extern "C" void kernel_launch(void* const* d_in, const int* in_sizes, int n_in,
                              void* d_out, int out_size, void* d_ws, size_t ws_size,
                              hipStream_t stream) {
    float* out = (float*)d_out;
    const int exp_sizes[14] = {4*64*32768, 4*512, 192*64, 64*512, 64, 192, 192,
                               4*32768, 64*64, 64*512, 64, 64, 64, 4*32768};
    bool ok = (n_in == 14) && (out_size == 4*64*32768);
    if (ok) for (int k = 0; k < 14; ++k) ok = ok && (in_sizes[k] == exp_sizes[k]);
    if (!ok) {  // shape-model tripwire: absmax ~= 1000
        k_zero<<<(out_size + 255) / 256, 256, 0, stream>>>(out, out_size);
        k_code<<<1, 1, 0, stream>>>(out, 1000.f);
        return;
    }
    if (ws_size < 395264) {  // ws tripwire (layout needs exactly 395264)
        k_zero<<<(out_size + 255) / 256, 256, 0, stream>>>(out, out_size);
        k_code<<<1, 1, 0, stream>>>(out, 2000.f + (float)(ws_size >> 20));
        return;
    }
    char* ws = (char*)d_ws;
    float* s_sty = (float*)ws;               //   2 KB
    float* S     = (float*)(ws + 2048);      // 128 KB  (4,8,32,32)
    float* wqkT  = (float*)(ws + 133120);    // 128 KB  (4,64e,128o)
    float* wvT   = (float*)(ws + 264192);    //  64 KB  (4,64e,64c)
    float* wpT   = (float*)(ws + 329728);    //  64 KB  (4,64i,64o)
    u16*   qk    = (u16*)d_out;              // 33.5 MB scratch, overwritten by k_out

    hipMemsetAsync(S, 0, 131072, stream);
    k_style  <<<4,    128,  0, stream>>>((const float*)d_in[1], (const float*)d_in[3],
                                         (const float*)d_in[4], (const float*)d_in[9],
                                         (const float*)d_in[10], s_sty);
    k_wnorm  <<<1024, 64,   0, stream>>>((const float*)d_in[2], (const float*)d_in[8],
                                         s_sty, wqkT, wvT, wpT);
    k_qk     <<<2048, 256,  0, stream>>>((const float*)d_in[0], wqkT,
                                         (const float*)d_in[5], (const float*)d_in[6],
                                         (const float*)d_in[7], qk);
    k_scores <<<1024, 256,  0, stream>>>(qk, S);
    k_softmax<<<32,   1024, 0, stream>>>(S);
    k_out    <<<1024, 256,  0, stream>>>((const float*)d_in[0], wvT,
                                         (const float*)d_in[5], (const float*)d_in[6],
                                         (const float*)d_in[7], S, wpT,
                                         (const float*)d_in[11], (const float*)d_in[12],
                                         (const float*)d_in[13], out);
    hipError_t e = hipGetLastError();
    if (e != hipSuccess) {  // launch-config tripwire: absmax ~= 3000 + code
        k_zero<<<(out_size + 255) / 256, 256, 0, stream>>>(out, out_size);
        k_code<<<1, 1, 0, stream>>>(out, 3000.f + (float)e);
    }
}

// Round 6
// 215.809 us; speedup vs baseline: 2.9411x; 1.0894x over previous
//
#include <hip/hip_runtime.h>

typedef unsigned short u16;
typedef unsigned int   u32;

#define PP 32768          // H*W*T
#define CC 64

__device__ __forceinline__ u16 f2b(float f) {
    u32 u; __builtin_memcpy(&u, &f, 4);
    u32 r = (u + 0x7FFFu + ((u >> 16) & 1u)) >> 16;
    return (u16)r;
}
__device__ __forceinline__ void unpack2(u32 v, float& lo, float& hi) {
    u32 a = v << 16; u32 b = v & 0xFFFF0000u;
    __builtin_memcpy(&lo, &a, 4); __builtin_memcpy(&hi, &b, 4);
}
__device__ __forceinline__ u32 pack2(float lo, float hi) {
    return (u32)f2b(lo) | ((u32)f2b(hi) << 16);
}

// ---------------- K1: style vectors ----------------------------------------
__global__ __launch_bounds__(128) void k_style(
        const float* __restrict__ style, const float* __restrict__ qkv_lw,
        const float* __restrict__ qkv_lb, const float* __restrict__ proj_lw,
        const float* __restrict__ proj_lb, float* __restrict__ s_out) {
    int b = blockIdx.x, tid = threadIdx.x;
    const float *lw, *lb; int i;
    if (tid < 64) { lw = qkv_lw; lb = qkv_lb; i = tid; }
    else          { lw = proj_lw; lb = proj_lb; i = tid - 64; }
    const float* st = style + b * 512;
    const float* w  = lw + (size_t)i * 512;
    float a0 = 0.f, a1 = 0.f, a2 = 0.f, a3 = 0.f;
    for (int k = 0; k < 512; k += 4) {
        float4 sv = *(const float4*)(st + k);
        float4 wv = *(const float4*)(w + k);
        a0 = fmaf(sv.x, wv.x, a0); a1 = fmaf(sv.y, wv.y, a1);
        a2 = fmaf(sv.z, wv.z, a2); a3 = fmaf(sv.w, wv.w, a3);
    }
    s_out[b * 128 + tid] = (a0 + a1) + (a2 + a3) + lb[i];
}

// ---------------- K2: normalized modulated weights, transposed -------------
// wqkT[b][e][o<128]; wvT[b][e][c]; wpT[b][i][o]
__global__ __launch_bounds__(64) void k_wnorm(
        const float* __restrict__ qkv_w, const float* __restrict__ proj_w,
        const float* __restrict__ s, float* __restrict__ wqkT,
        float* __restrict__ wvT, float* __restrict__ wpT) {
    int id = blockIdx.x;           // 4 * 256
    int b = id >> 8, o = id & 255, i = threadIdx.x;
    float wv;
    if (o < 192) wv = qkv_w[o * 64 + i] * s[b * 128 + i];
    else         wv = proj_w[(o - 192) * 64 + i] * s[b * 128 + 64 + i];
    float sq = wv * wv;
    #pragma unroll
    for (int off = 32; off > 0; off >>= 1) sq += __shfl_xor(sq, off, 64);
    float val = wv * rsqrtf(sq + 1e-8f);
    if (o < 128)      wqkT[((size_t)b * 64 + i) * 128 + o]      = val;
    else if (o < 192) wvT [((size_t)b * 64 + i) * 64 + (o-128)] = val;
    else              wpT [((size_t)b * 64 + i) * 64 + (o-192)] = val;
}

// ---------------- K3: FUSED q,k recompute + scores -------------------------
// grid (b, n, chunk32hw) = 1024; q,k in regs -> LDS; rnd5-proven scores phase.
__global__ __launch_bounds__(256) void k_fscores(
        const float* __restrict__ x, const float* __restrict__ wqkT,
        const float* __restrict__ qnp, const float* __restrict__ qbp,
        const float* __restrict__ qnoise, float* __restrict__ S) {
    int bidx = blockIdx.x;
    int b = bidx >> 8, n = (bidx >> 5) & 7, chunk = bidx & 31;
    int tid = threadIdx.x;
    __shared__ float q_lds[8192];     // [c<8][hw_l*32+t]
    __shared__ float k_lds[8192];
    // ---- qk phase: thread owns 4 consecutive p, all 16 channels in regs ----
    float qa[8][4], ka[8][4];
    #pragma unroll
    for (int c = 0; c < 8; ++c)
        #pragma unroll
        for (int j = 0; j < 4; ++j) { qa[c][j] = 0.f; ka[c][j] = 0.f; }
    const float* xb = x + (size_t)b * CC * PP + chunk * 1024 + tid * 4;
    const float* wb = wqkT + (size_t)b * 8192 + n * 8;
    #pragma unroll 2
    for (int e = 0; e < 64; ++e) {
        float4 xv = *(const float4*)(xb + (size_t)e * PP);
        float xr[4] = {xv.x, xv.y, xv.z, xv.w};
        const float* wr = wb + e * 128;          // wave-uniform -> s_load
        #pragma unroll
        for (int c = 0; c < 8; ++c) {
            float wq_ = wr[c], wk_ = wr[64 + c];
            #pragma unroll
            for (int j = 0; j < 4; ++j) {
                qa[c][j] = fmaf(wq_, xr[j], qa[c][j]);
                ka[c][j] = fmaf(wk_, xr[j], ka[c][j]);
            }
        }
    }
    {
        float4 nz4 = *(const float4*)(qnoise + (size_t)b * PP + chunk * 1024 + tid * 4);
        float nz[4] = {nz4.x, nz4.y, nz4.z, nz4.w};
        #pragma unroll
        for (int c = 0; c < 8; ++c) {
            float qn = qnp[n * 8 + c], qb_ = qbp[n * 8 + c];
            float kn = qnp[64 + n * 8 + c], kb_ = qbp[64 + n * 8 + c];
            float4 qo, ko;
            qo.x = qa[c][0] + qn * nz[0] + qb_;  ko.x = ka[c][0] + kn * nz[0] + kb_;
            qo.y = qa[c][1] + qn * nz[1] + qb_;  ko.y = ka[c][1] + kn * nz[1] + kb_;
            qo.z = qa[c][2] + qn * nz[2] + qb_;  ko.z = ka[c][2] + kn * nz[2] + kb_;
            qo.w = qa[c][3] + qn * nz[3] + qb_;  ko.w = ka[c][3] + kn * nz[3] + kb_;
            *(float4*)&q_lds[c * 1024 + tid * 4] = qo;
            *(float4*)&k_lds[c * 1024 + tid * 4] = ko;
        }
    }
    __syncthreads();
    // ---- scores phase (round-5 proven) ----
    int wave = tid >> 6, lane = tid & 63;
    int ig = lane >> 3, jg = lane & 7;
    float acc[16];
    #pragma unroll
    for (int q = 0; q < 16; ++q) acc[q] = 0.f;
    #pragma unroll 4
    for (int i = 0; i < 64; ++i) {
        int e = wave * 64 + i, c = e >> 5, hl = e & 31;
        float4 qv = *(const float4*)&q_lds[c * 1024 + hl * 32 + ig * 4];
        float4 kv = *(const float4*)&k_lds[c * 1024 + hl * 32 + jg * 4];
        float qa4[4] = {qv.x, qv.y, qv.z, qv.w};
        float ka4[4] = {kv.x, kv.y, kv.z, kv.w};
        #pragma unroll
        for (int ii = 0; ii < 4; ++ii)
            #pragma unroll
            for (int jj = 0; jj < 4; ++jj)
                acc[ii * 4 + jj] = fmaf(qa4[ii], ka4[jj], acc[ii * 4 + jj]);
    }
    __syncthreads();                  // q_lds dead -> reduction scratch
    #pragma unroll
    for (int t = 0; t < 16; ++t) q_lds[t * 256 + tid] = acc[t];
    __syncthreads();
    if (wave == 0) {
        float* Sb = S + ((size_t)b * 8 + n) * 1024;
        #pragma unroll
        for (int t = 0; t < 16; ++t) {
            float s2 = q_lds[t * 256 + lane]       + q_lds[t * 256 + 64 + lane]
                     + q_lds[t * 256 + 128 + lane] + q_lds[t * 256 + 192 + lane];
            int ii = t >> 2, jj = t & 3;
            atomicAdd(&Sb[(ig * 4 + ii) * 32 + jg * 4 + jj], s2);
        }
    }
}

// ---------------- K4: ALiBi + mask + softmax -> bf16 P ---------------------
__global__ __launch_bounds__(1024) void k_softmax(
        const float* __restrict__ S, u16* __restrict__ P16g) {
    int bn = blockIdx.x;                // b*8 + n
    int n = bn & 7;
    int tid = threadIdx.x, i = tid >> 5, j = tid & 31;
    const float* row = S + (size_t)bn * 1024 + i * 32;
    float v = row[j] * 0.011048543456039806f;      // 1/sqrt(8192)
    float slope = exp2f(-(float)(n + 1));
    v -= slope * fabsf((float)(i - j));
    if (j <= i) v = -1e18f;                        // tril (incl. diag) masked
    float m = v;
    #pragma unroll
    for (int off = 16; off > 0; off >>= 1) m = fmaxf(m, __shfl_xor(m, off, 32));
    float e = expf(v - m);
    float s2 = e;
    #pragma unroll
    for (int off = 16; off > 0; off >>= 1) s2 += __shfl_xor(s2, off, 32);
    P16g[(size_t)bn * 1024 + i * 32 + j] = f2b(e / s2);
}

// ---------------- K5: v recompute + PV + proj ------------------------------
// grid (b, hwblk4) = 1024, 256 thr. LDS 72.7 KB -> 2 blocks/CU.
// ph1: thread (ig:4vch, hwl, th:8t): 1 b128 : 16 FMA. v -> bf16 LDS.
// ph2: thread (p2:2ich, hwl2, th2:16t): P bf16, v regs -> As (fp32, uni).
// ph3: proj as round 5, As reads scalarized.
__global__ __launch_bounds__(256) void k_out(
        const float* __restrict__ x, const float* __restrict__ wvT,
        const float* __restrict__ qnp, const float* __restrict__ qbp,
        const float* __restrict__ qnoise, const u16* __restrict__ P16g,
        const float* __restrict__ wpT, const float* __restrict__ pnp,
        const float* __restrict__ pbp, const float* __restrict__ pnoise,
        float* __restrict__ out) {
    int bidx = blockIdx.x;
    int b = bidx >> 8, hw0 = (bidx & 255) * 4;
    int tid = threadIdx.x;
    __shared__ u32   P32s[8 * 576];     // [h][t*18 + jp] packed bf16 pairs
    __shared__ float uni[9216];         // ph1: xs[e][hwl*36+t] (rows 144); ph2/3: As[i*132+hwl*33+t]
    __shared__ u32   v32s[64 * 68];     // [ich][hwl*17 + t/2] packed bf16 pairs
    // ---- stage P (bf16 pairs) ----
    const u32* Pg32 = (const u32*)(P16g + (size_t)b * 8192);
    #pragma unroll
    for (int r = 0; r < 16; ++r) {
        int idx = r * 256 + tid;              // 0..4095 u32
        int h = idx >> 9, rem = idx & 511, t = rem >> 4, jp = rem & 15;
        P32s[h * 576 + t * 18 + jp] = Pg32[idx];
    }
    // ---- stage x: uni[e*144 + hwl*36 + t] ----
    const float* xb = x + (size_t)b * CC * PP + (size_t)hw0 * 32;
    #pragma unroll
    for (int r4 = 0; r4 < 8; ++r4) {
        int idx = r4 * 256 + tid;             // 0..2047 float4s
        int e = idx >> 5, rem = idx & 31, hwl = rem >> 3, tq = rem & 7;
        float4 xv = *(const float4*)(xb + (size_t)e * PP + rem * 4);
        *(float4*)&uni[e * 144 + hwl * 36 + tq * 4] = xv;
    }
    __syncthreads();
    // ---- phase 1: v = W x (4 vch x 8 t per thread) ----
    {
        int ig = tid >> 4, r = tid & 15, hwl = r >> 2, th = r & 3, t0 = th * 8;
        float acc[4][8];
        #pragma unroll
        for (int ii = 0; ii < 4; ++ii)
            #pragma unroll
            for (int j = 0; j < 8; ++j) acc[ii][j] = 0.f;
        const float* wvb = wvT + (size_t)b * 4096 + ig * 4;
        #pragma unroll 2
        for (int e = 0; e < 64; ++e) {
            float4 w4 = *(const float4*)(wvb + e * 64);
            float wr[4] = {w4.x, w4.y, w4.z, w4.w};
            const float* xp = &uni[e * 144 + hwl * 36 + t0];
            float4 xa = *(const float4*)xp;
            float4 xc = *(const float4*)(xp + 4);
            float x8[8] = {xa.x, xa.y, xa.z, xa.w, xc.x, xc.y, xc.z, xc.w};
            #pragma unroll
            for (int ii = 0; ii < 4; ++ii)
                #pragma unroll
                for (int j = 0; j < 8; ++j)
                    acc[ii][j] = fmaf(wr[ii], x8[j], acc[ii][j]);
        }
        float4 np4 = *(const float4*)(qnp + 128 + ig * 4);
        float4 bp4 = *(const float4*)(qbp + 128 + ig * 4);
        float npr[4] = {np4.x, np4.y, np4.z, np4.w};
        float bpr[4] = {bp4.x, bp4.y, bp4.z, bp4.w};
        const float* nzp = qnoise + (size_t)b * PP + (size_t)(hw0 + hwl) * 32 + t0;
        float4 na = *(const float4*)nzp;
        float4 nc = *(const float4*)(nzp + 4);
        float nz[8] = {na.x, na.y, na.z, na.w, nc.x, nc.y, nc.z, nc.w};
        #pragma unroll
        for (int ii = 0; ii < 4; ++ii) {
            int ich = ig * 4 + ii;
            #pragma unroll
            for (int q = 0; q < 4; ++q) {
                float y0 = acc[ii][2*q]   + npr[ii] * nz[2*q]   + bpr[ii];
                float y1 = acc[ii][2*q+1] + npr[ii] * nz[2*q+1] + bpr[ii];
                v32s[ich * 68 + hwl * 17 + th * 4 + q] = pack2(y0, y1);
            }
        }
    }
    __syncthreads();   // v32s complete; uni (xs) dead -> becomes As
    // ---- phase 2: A[ich][hwl][t] = sum_j P[h][t][j] v[ich][hwl][j] ----
    {
        int p2 = tid >> 3, r3 = tid & 7, hwl2 = r3 >> 1, ts = (r3 & 1) * 16;
        int h = p2 >> 2;
        float vj[2][32];
        #pragma unroll
        for (int d = 0; d < 2; ++d) {
            const u32* vp = &v32s[(2 * p2 + d) * 68 + hwl2 * 17];
            #pragma unroll
            for (int jp = 0; jp < 16; ++jp)
                unpack2(vp[jp], vj[d][2*jp], vj[d][2*jp+1]);
        }
        float acc2[2][16];
        #pragma unroll
        for (int d = 0; d < 2; ++d)
            #pragma unroll
            for (int i = 0; i < 16; ++i) acc2[d][i] = 0.f;
        #pragma unroll 2
        for (int i = 0; i < 16; ++i) {
            const u32* Pr = &P32s[h * 576 + (ts + i) * 18];
            #pragma unroll
            for (int jp = 0; jp < 16; ++jp) {
                float p0, p1; unpack2(Pr[jp], p0, p1);
                acc2[0][i] = fmaf(p0, vj[0][2*jp], acc2[0][i]);
                acc2[0][i] = fmaf(p1, vj[0][2*jp+1], acc2[0][i]);
                acc2[1][i] = fmaf(p0, vj[1][2*jp], acc2[1][i]);
                acc2[1][i] = fmaf(p1, vj[1][2*jp+1], acc2[1][i]);
            }
        }
        #pragma unroll
        for (int d = 0; d < 2; ++d)
            #pragma unroll
            for (int i = 0; i < 16; ++i)
                uni[(2 * p2 + d) * 132 + hwl2 * 33 + ts + i] = acc2[d][i];
    }
    __syncthreads();
    // ---- phase 3: proj ----
    {
        int og = tid >> 6, lane = tid & 63;
        int tt = lane & 31, rep = lane >> 5;
        int ogu = __builtin_amdgcn_readfirstlane(og);
        const float* wpt = wpT + (size_t)b * 4096 + ogu * 16;
        float acc[16][2];
        #pragma unroll
        for (int oo = 0; oo < 16; ++oo) { acc[oo][0] = 0.f; acc[oo][1] = 0.f; }
        #pragma unroll 4
        for (int i = 0; i < 64; ++i) {
            float a0 = uni[i * 132 + (rep * 2) * 33 + tt];
            float a1 = uni[i * 132 + (rep * 2) * 33 + 33 + tt];
            const float* wr = wpt + i * 64;   // wave-uniform -> s_load
            #pragma unroll
            for (int oo = 0; oo < 16; ++oo) {
                acc[oo][0] = fmaf(wr[oo], a0, acc[oo][0]);
                acc[oo][1] = fmaf(wr[oo], a1, acc[oo][1]);
            }
        }
        float nz0 = pnoise[(size_t)b * PP + (size_t)(hw0 + rep * 2) * 32 + tt];
        float nz1 = pnoise[(size_t)b * PP + (size_t)(hw0 + rep * 2 + 1) * 32 + tt];
        #pragma unroll
        for (int oo = 0; oo < 16; ++oo) {
            int o = ogu * 16 + oo;
            float npv = pnp[o], bpv = pbp[o];
            size_t base = (size_t)(b * 64 + o) * PP + tt;
            out[base + (size_t)(hw0 + rep * 2) * 32]     = acc[oo][0] + npv * nz0 + bpv;
            out[base + (size_t)(hw0 + rep * 2 + 1) * 32] = acc[oo][1] + npv * nz1 + bpv;
        }
    }
}

// ---------------- sentinels ------------------------------------------------
__global__ __launch_bounds__(256) void k_zero(float* __restrict__ out, int n) {
    int i = blockIdx.x * 256 + threadIdx.x;
    if (i < n) out[i] = 0.f;
}
__global__ void k_code(float* __restrict__ out, float code) { out[0] = code; }

extern "C" void kernel_launch(void* const* d_in, const int* in_sizes, int n_in,
                              void* d_out, int out_size, void* d_ws, size_t ws_size,
                              hipStream_t stream) {
    float* out = (float*)d_out;
    const int exp_sizes[14] = {4*64*32768, 4*512, 192*64, 64*512, 64, 192, 192,
                               4*32768, 64*64, 64*512, 64, 64, 64, 4*32768};
    bool ok = (n_in == 14) && (out_size == 4*64*32768);
    if (ok) for (int k = 0; k < 14; ++k) ok = ok && (in_sizes[k] == exp_sizes[k]);
    if (!ok) {
        k_zero<<<(out_size + 255) / 256, 256, 0, stream>>>(out, out_size);
        k_code<<<1, 1, 0, stream>>>(out, 1000.f);
        return;
    }
    if (ws_size < 395264) {
        k_zero<<<(out_size + 255) / 256, 256, 0, stream>>>(out, out_size);
        k_code<<<1, 1, 0, stream>>>(out, 2000.f + (float)(ws_size >> 20));
        return;
    }
    char* ws = (char*)d_ws;
    float* s_sty = (float*)ws;               //   2 KB
    float* S     = (float*)(ws + 2048);      // 128 KB  (4,8,32,32)
    float* wqkT  = (float*)(ws + 133120);    // 128 KB  (4,64e,128o)
    u16*   P16g  = (u16*)(ws + 133120);      //  64 KB  alias: wqkT dead after k_fscores
    float* wvT   = (float*)(ws + 264192);    //  64 KB  (4,64e,64c)
    float* wpT   = (float*)(ws + 329728);    //  64 KB  (4,64i,64o)

    hipMemsetAsync(S, 0, 131072, stream);
    k_style  <<<4,    128,  0, stream>>>((const float*)d_in[1], (const float*)d_in[3],
                                         (const float*)d_in[4], (const float*)d_in[9],
                                         (const float*)d_in[10], s_sty);
    k_wnorm  <<<1024, 64,   0, stream>>>((const float*)d_in[2], (const float*)d_in[8],
                                         s_sty, wqkT, wvT, wpT);
    k_fscores<<<1024, 256,  0, stream>>>((const float*)d_in[0], wqkT,
                                         (const float*)d_in[5], (const float*)d_in[6],
                                         (const float*)d_in[7], S);
    k_softmax<<<32,   1024, 0, stream>>>(S, P16g);
    k_out    <<<1024, 256,  0, stream>>>((const float*)d_in[0], wvT,
                                         (const float*)d_in[5], (const float*)d_in[6],
                                         (const float*)d_in[7], P16g, wpT,
                                         (const float*)d_in[11], (const float*)d_in[12],
                                         (const float*)d_in[13], out);
    hipError_t e = hipGetLastError();
    if (e != hipSuccess) {
        k_zero<<<(out_size + 255) / 256, 256, 0, stream>>>(out, out_size);
        k_code<<<1, 1, 0, stream>>>(out, 3000.f + (float)e);
    }
}